// Round 1
// baseline (291.515 us; speedup 1.0000x reference)
//
#include <hip/hip_runtime.h>
#include <hip/hip_bf16.h>

typedef unsigned short u16;
typedef short short8 __attribute__((ext_vector_type(8)));
typedef float f32x4 __attribute__((ext_vector_type(4)));

// EMBED=256, NH=8, HD=32, NPAIR=16, K_PER_Q=164; levels 128,64,32,16
// compact rows/batch = 16384+4096+1024+256 = 21760
#define ROWS_PER_BATCH 21760
#define TOT_ROWS 43520

__device__ __forceinline__ u16 f2bf(float f){
  unsigned u = __builtin_bit_cast(unsigned, f);
  u += 0x7FFFu + ((u >> 16) & 1u);
  return (u16)(u >> 16);
}
__device__ __forceinline__ float bf2f(u16 h){
  return __builtin_bit_cast(float, ((unsigned)h) << 16);
}
__device__ __forceinline__ float bflo(unsigned u){ return __builtin_bit_cast(float, u << 16); }
__device__ __forceinline__ float bfhi(unsigned u){ return __builtin_bit_cast(float, u & 0xFFFF0000u); }
__device__ __forceinline__ unsigned pk2bf(float a, float b){
  __hip_bfloat162 h = __float22bfloat162_rn(make_float2(a, b));
  union { __hip_bfloat162 h2; unsigned u; } cv; cv.h2 = h; return cv.u;
}

// ---------- prep: weight pack (blocks 0..127) + LayerNorm (blocks 128..) ----------
// packed[((cg*8 + kk)*64 + lane)*8 + j] = W[kk*32 + (lane>>4)*8 + j][cg*16 + (lane&15)]
__global__ __launch_bounds__(256) void prep_kernel(
    const float* __restrict__ qw, const float* __restrict__ kw,
    const float* __restrict__ vw, const float* __restrict__ ow,
    const float* __restrict__ q, const float* __restrict__ nw,
    const float* __restrict__ nb,
    u16* __restrict__ wtq, u16* __restrict__ wtk,
    u16* __restrict__ wtv, u16* __restrict__ wto, u16* __restrict__ x){
  const int bx = blockIdx.x;
  const int t = threadIdx.x;
  if (bx < 128){
    int e = bx * 256 + t;
    int which = e >> 13;
    int r = e & 8191;
    int cg = r >> 9;
    int kk = (r >> 6) & 7;
    int lane = r & 63;
    int quad = lane >> 4, mn = lane & 15;
    const float* s = which == 0 ? qw : which == 1 ? kw : which == 2 ? vw : ow;
    u16* d       = which == 0 ? wtq : which == 1 ? wtk : which == 2 ? wtv : wto;
    const float* base = s + (kk * 32 + quad * 8) * 256 + cg * 16 + mn;
    float e8[8];
    #pragma unroll
    for (int j = 0; j < 8; ++j) e8[j] = base[j * 256];
    uint4 o = { pk2bf(e8[0], e8[1]), pk2bf(e8[2], e8[3]),
                pk2bf(e8[4], e8[5]), pk2bf(e8[6], e8[7]) };
    *(uint4*)(d + (size_t)r * 8) = o;
  } else {
    const int row = (bx - 128) * 4 + (t >> 6);
    const int lane = t & 63;
    const float4 v = *(const float4*)(q + (size_t)row * 256 + lane * 4);
    float s1 = v.x + v.y + v.z + v.w;
    float s2 = v.x*v.x + v.y*v.y + v.z*v.z + v.w*v.w;
    #pragma unroll
    for (int o = 32; o > 0; o >>= 1){
      s1 += __shfl_xor(s1, o);
      s2 += __shfl_xor(s2, o);
    }
    float mu = s1 * (1.0f / 256.0f);
    float var = s2 * (1.0f / 256.0f) - mu * mu;
    float rs = rsqrtf(var + 1e-5f);
    const float4 wv = *(const float4*)(nw + lane * 4);
    const float4 bv = *(const float4*)(nb + lane * 4);
    float o0 = (v.x - mu) * rs * wv.x + bv.x;
    float o1 = (v.y - mu) * rs * wv.y + bv.y;
    float o2 = (v.z - mu) * rs * wv.z + bv.z;
    float o3 = (v.w - mu) * rs * wv.w + bv.w;
    uint2 pk = { pk2bf(o0, o1), pk2bf(o2, o3) };
    *(uint2*)(x + (size_t)row * 256 + lane * 4) = pk;
  }
}

// ---------- K+V map projection, fused K-RoPE. 1 wave/block, 16 rows, K AND V. ----------
// grid 2720 x 64 thr. Barrier-free; A fragments loaded once, reused for K and V.
__global__ __launch_bounds__(64, 4) void kv_gemm(const float* __restrict__ fm,
        const u16* __restrict__ wtkp, const u16* __restrict__ wtvp,
        const float* __restrict__ rope,
        u16* __restrict__ krot, u16* __restrict__ vmap){
  __shared__ float slab[16][66];
  __shared__ unsigned sh_cs[16][16];

  const int lane = threadIdx.x;
  const int row0 = blockIdx.x * 16;

  const int b = row0 / ROWS_PER_BATCH;
  const int rr = row0 - b * ROWS_PER_BATCH;
  int l, loff;
  if (rr < 16384)      { l = 0; loff = 0; }
  else if (rr < 20480) { l = 1; loff = 16384; }
  else if (rr < 21504) { l = 2; loff = 20480; }
  else                 { l = 3; loff = 21504; }
  const int logW = 7 - l;
  const int Wm1 = (128 >> l) - 1;
  const int cell0 = rr - loff;
  const float* fmbase = fm + (size_t)(b * 4 + l) * (128 * 128 * 256);

  const int mn = lane & 15;
  const int quad = lane >> 4;

  // A fragments straight from global (fp32 -> bf16 in regs)
  short8 af[8];
  {
    int cell = cell0 + mn;
    int y = cell >> logW, x = cell & Wm1;
    const float* arow = fmbase + (((y << 7) + x) << 8) + quad * 8;
    #pragma unroll
    for (int kk = 0; kk < 8; ++kk){
      float4 a0 = *(const float4*)(arow + kk * 32);
      float4 a1 = *(const float4*)(arow + kk * 32 + 4);
      union { short8 s; uint4 u; } cv;
      cv.u = (uint4){ pk2bf(a0.x, a0.y), pk2bf(a0.z, a0.w),
                      pk2bf(a1.x, a1.y), pk2bf(a1.z, a1.w) };
      af[kk] = cv.s;
    }
  }

  // cos/sin table: 16 rows x 16 pairs
  #pragma unroll
  for (int i = 0; i < 4; ++i){
    int id = i * 64 + lane;
    int lr = id >> 4, p = id & 15;
    int cell = cell0 + lr;
    int i0 = cell >> logW;
    int i1 = cell & Wm1;
    float fs = (float)(1 << l);
    float kx = ((float)i0 + 0.5f) * fs;
    float ky = ((float)i1 + 0.5f) * fs;
    float ang = kx * rope[p] + ky * rope[16 + p] + (float)l * rope[32 + p];
    sh_cs[lr][p] = pk2bf(__cosf(ang), __sinf(ang));
  }

  for (int m = 0; m < 2; ++m){
    const u16* wtp = m ? wtvp : wtkp;
    u16* outp = m ? vmap : krot;
    for (int cs2 = 0; cs2 < 4; ++cs2){
      const u16* wb = wtp + (size_t)((cs2 * 4 * 8) * 64 + lane) * 8;
      short8 bc[4], bn[4];
      #pragma unroll
      for (int tl = 0; tl < 4; ++tl)
        bc[tl] = *(const short8*)(wb + (size_t)(tl * 8) * 64 * 8);
      f32x4 acc[4];
      #pragma unroll
      for (int i = 0; i < 4; ++i) acc[i] = (f32x4){0.f, 0.f, 0.f, 0.f};
      #pragma unroll
      for (int kk = 0; kk < 8; ++kk){
        if (kk < 7){
          #pragma unroll
          for (int tl = 0; tl < 4; ++tl)
            bn[tl] = *(const short8*)(wb + (size_t)(tl * 8 + kk + 1) * 64 * 8);
        }
        #pragma unroll
        for (int tl = 0; tl < 4; ++tl)
          acc[tl] = __builtin_amdgcn_mfma_f32_16x16x32_bf16(af[kk], bc[tl], acc[tl], 0, 0, 0);
        #pragma unroll
        for (int tl = 0; tl < 4; ++tl) bc[tl] = bn[tl];
      }
      // wave-local epilogue: slab transpose -> (RoPE) -> coalesced bf16 store
      #pragma unroll
      for (int tl = 0; tl < 4; ++tl)
        #pragma unroll
        for (int r = 0; r < 4; ++r)
          slab[quad * 4 + r][tl * 16 + mn] = acc[tl][r];
      #pragma unroll
      for (int i = 0; i < 8; ++i){
        int pi = i * 64 + lane;
        int row = pi >> 5;
        int pl = pi & 31;
        float2 kv2 = *(const float2*)&slab[row][pl * 2];
        unsigned o;
        if (m == 0){
          unsigned csn = sh_cs[row][pl & 15];
          float c = bflo(csn), s = bfhi(csn);
          o = pk2bf(kv2.x * c - kv2.y * s, kv2.x * s + kv2.y * c);
        } else {
          o = pk2bf(kv2.x, kv2.y);
        }
        *(unsigned*)(outp + (size_t)(row0 + row) * 256 + cs2 * 64 + pl * 2) = o;
      }
    }
  }
}

// ---------- barrier-free MFMA GEMM: out[M][256] = A(bf16) @ WT (+resid) ----------
__global__ __launch_bounds__(256) void gemm_xw(const u16* __restrict__ A,
        const u16* __restrict__ wt, const float* __restrict__ resid,
        float* __restrict__ out){
  const int t = threadIdx.x;
  const int row0 = blockIdx.x * 16;
  const int wv = t >> 6;
  const int lane = t & 63;
  const int mn = lane & 15;
  const int quad = lane >> 4;
  const int cg = blockIdx.y * 4 + wv;

  short8 af[8];
  {
    const u16* arow = A + (size_t)(row0 + mn) * 256 + quad * 8;
    #pragma unroll
    for (int kk = 0; kk < 8; ++kk)
      af[kk] = *(const short8*)(arow + kk * 32);
  }
  const u16* wb = wt + (size_t)((cg * 8) * 64 + lane) * 8;
  short8 bc = *(const short8*)wb;
  f32x4 acc = (f32x4){0.f, 0.f, 0.f, 0.f};
  #pragma unroll
  for (int kk = 0; kk < 8; ++kk){
    short8 bn;
    if (kk < 7) bn = *(const short8*)(wb + (size_t)(kk + 1) * 64 * 8);
    acc = __builtin_amdgcn_mfma_f32_16x16x32_bf16(af[kk], bc, acc, 0, 0, 0);
    bc = bn;
  }
  const int col = cg * 16 + mn;
  #pragma unroll
  for (int r = 0; r < 4; ++r){
    int row = row0 + quad * 4 + r;
    float val = acc[r];
    if (resid) val += resid[(size_t)row * 256 + col];
    out[(size_t)row * 256 + col] = val;
  }
}

// ---------- attention core v2: ONE BLOCK (4 waves) PER QUERY ----------
// grid n_q x 256 thr. Each wave owns 41 of the 164 keys -> 4x wave-level
// parallelism and 4x shorter serial gather chains vs the 1-wave/query design.
// Logits live in registers (6/lane); softmax via wave-local max/sum + tiny
// LDS combine; PV does 2 keys/iter with 16B loads and one shfl_xor(32) merge.
__global__ __launch_bounds__(256, 4) void attn3(
    const float* __restrict__ qraw, const float* __restrict__ qsp,
    const float* __restrict__ rope, const int* __restrict__ qbo, int nbo,
    const u16* __restrict__ krot, const u16* __restrict__ vmap,
    u16* __restrict__ ao){
  __shared__ float sh_q[8][33];
  __shared__ int   sh_row[168];
  __shared__ float sh_lg[168][8];
  __shared__ float sh_wmax[4][8];
  __shared__ float sh_psum[4][8];
  __shared__ float sh_pv[4][256];

  const int t = threadIdx.x;
  const int w = t >> 6;
  const int lane = t & 63;
  const int qi = blockIdx.x;

  int bidx = 0;
  for (int j = 1; j < nbo; ++j) if (qi >= qbo[j]) bidx = j;
  const float p0 = qsp[qi * 2 + 0];
  const float p1 = qsp[qi * 2 + 1];

  // q RoPE (1/sqrt(32) folded); 256 threads cover 256 dims in one shot
  {
    int d = t;
    float qv = qraw[(size_t)qi * 256 + d];
    int p = (d & 31) >> 1;
    float ang = p0 * rope[p] + p1 * rope[16 + p];
    float c = __cosf(ang), s = __sinf(ang);
    float partner = __shfl_xor(qv, 1);
    float val = (d & 1) ? (partner * s + qv * c) : (qv * c - partner * s);
    sh_q[d >> 5][d & 31] = val * 0.17677669529663687f;
  }

  // key rows + validity (164 threads, one key each)
  if (t < 164){
    int kk = t;
    int l, dy, dx, loff;
    if (kk < 9)       { l = 0; int j = kk;      dy = j / 3 - 1; dx = j % 3 - 1; loff = 0; }
    else if (kk < 34) { l = 1; int j = kk - 9;  dy = j / 5 - 2; dx = j % 5 - 2; loff = 16384; }
    else if (kk < 83) { l = 2; int j = kk - 34; dy = j / 7 - 3; dx = j % 7 - 3; loff = 20480; }
    else              { l = 3; int j = kk - 83; dy = j / 9 - 4; dx = j % 9 - 4; loff = 21504; }
    float sc = 1.0f / (float)(1 << l);
    int i0 = (int)floorf(p0 * sc) + dy;
    int i1 = (int)floorf(p1 * sc) + dx;
    int W = 128 >> l;
    sh_row[kk] = (i0 < 0 || i0 >= W || i1 < 0 || i1 >= W)
              ? -1 : bidx * ROWS_PER_BATCH + loff + (i0 << (7 - l)) + i1;
  }
  __syncthreads();   // B1: sh_q + sh_row visible to all waves

  // logits: wave w owns keys [w*41, w*41+41); lane = (ksub, h)
  const int h = lane & 7;
  const int ksub = lane >> 3;
  const int kbase = w * 41;

  float qreg[32];
  #pragma unroll
  for (int j = 0; j < 32; ++j) qreg[j] = sh_q[h][j];

  int rown[6];
  #pragma unroll
  for (int p = 0; p < 6; ++p){
    int i = p * 8 + ksub;
    rown[p] = (i < 41) ? sh_row[kbase + i] : -1;
  }

  float lgr[6];
  #pragma unroll
  for (int p = 0; p < 6; ++p){
    float lg = -1e9f;
    int row = rown[p];
    if (row >= 0){
      const uint4* kp = (const uint4*)(krot + (size_t)row * 256 + h * 32);
      uint4 A0 = kp[0], A1 = kp[1], A2 = kp[2], A3 = kp[3];
      unsigned uu[16];
      uu[0]=A0.x; uu[1]=A0.y; uu[2]=A0.z; uu[3]=A0.w;
      uu[4]=A1.x; uu[5]=A1.y; uu[6]=A1.z; uu[7]=A1.w;
      uu[8]=A2.x; uu[9]=A2.y; uu[10]=A2.z; uu[11]=A2.w;
      uu[12]=A3.x; uu[13]=A3.y; uu[14]=A3.z; uu[15]=A3.w;
      lg = 0.f;
      #pragma unroll
      for (int j = 0; j < 16; ++j)
        lg += qreg[2*j] * bflo(uu[j]) + qreg[2*j+1] * bfhi(uu[j]);
    }
    lgr[p] = lg;
  }

  // softmax: wave-local max per head (xor 8/16/32 butterflies preserve h)
  float mx = fmaxf(fmaxf(fmaxf(lgr[0], lgr[1]), fmaxf(lgr[2], lgr[3])),
                   fmaxf(lgr[4], lgr[5]));
  #pragma unroll
  for (int o = 8; o < 64; o <<= 1) mx = fmaxf(mx, __shfl_xor(mx, o));
  if (ksub == 0) sh_wmax[w][h] = mx;
  __syncthreads();   // B2: cross-wave max

  const float gmx = fmaxf(fmaxf(sh_wmax[0][h], sh_wmax[1][h]),
                          fmaxf(sh_wmax[2][h], sh_wmax[3][h]));
  float ssum = 0.f;
  #pragma unroll
  for (int p = 0; p < 6; ++p){
    int i = p * 8 + ksub;
    if (i < 41){
      float e = __expf(lgr[p] - gmx);   // invalid keys -> exactly 0
      sh_lg[kbase + i][h] = e;
      ssum += e;
    }
  }
  #pragma unroll
  for (int o = 8; o < 64; o <<= 1) ssum += __shfl_xor(ssum, o);
  if (ksub == 0) sh_psum[w][h] = ssum;
  __syncthreads();   // B3: cross-wave partial sums

  // PV over this wave's 41 keys: 2 keys/iter, lane = (parity, 8-dim group)
  const int c = lane & 31;
  const int p2 = lane >> 5;
  const int hh = c >> 2;
  const float invd = 1.0f / (sh_psum[0][hh] + sh_psum[1][hh] +
                             sh_psum[2][hh] + sh_psum[3][hh]);
  float a[8] = {0.f, 0.f, 0.f, 0.f, 0.f, 0.f, 0.f, 0.f};
  #pragma unroll
  for (int ii = 0; ii < 21; ++ii){
    int i = ii * 2 + p2;
    bool vld = i < 41;
    int kk = kbase + (vld ? i : 0);
    float e = vld ? sh_lg[kk][hh] : 0.f;
    int row = vld ? sh_row[kk] : -1;
    int rc = row < 0 ? 0 : row;
    uint4 vv = *(const uint4*)(vmap + (size_t)rc * 256 + c * 8);
    a[0] += e * bflo(vv.x); a[1] += e * bfhi(vv.x);
    a[2] += e * bflo(vv.y); a[3] += e * bfhi(vv.y);
    a[4] += e * bflo(vv.z); a[5] += e * bfhi(vv.z);
    a[6] += e * bflo(vv.w); a[7] += e * bfhi(vv.w);
  }
  #pragma unroll
  for (int j = 0; j < 8; ++j) a[j] += __shfl_xor(a[j], 32);
  if (p2 == 0){
    #pragma unroll
    for (int j = 0; j < 8; ++j) sh_pv[w][c * 8 + j] = a[j] * invd;
  }
  __syncthreads();   // B4: wave partials in LDS

  if (t < 128){
    int d0 = t * 2;
    float s0 = sh_pv[0][d0]     + sh_pv[1][d0]     + sh_pv[2][d0]     + sh_pv[3][d0];
    float s1 = sh_pv[0][d0 + 1] + sh_pv[1][d0 + 1] + sh_pv[2][d0 + 1] + sh_pv[3][d0 + 1];
    *(unsigned*)(ao + (size_t)qi * 256 + d0) = pk2bf(s0, s1);
  }
}

extern "C" void kernel_launch(void* const* d_in, const int* in_sizes, int n_in,
                              void* d_out, int out_size, void* d_ws, size_t ws_size,
                              hipStream_t stream) {
  (void)n_in; (void)out_size; (void)ws_size;
  const float* query  = (const float*)d_in[0];
  const float* qsp    = (const float*)d_in[1];
  const float* fm     = (const float*)d_in[2];
  const float* norm_w = (const float*)d_in[3];
  const float* norm_b = (const float*)d_in[4];
  const float* q_w    = (const float*)d_in[5];
  const float* k_w    = (const float*)d_in[6];
  const float* v_w    = (const float*)d_in[7];
  const float* out_w  = (const float*)d_in[8];
  const float* rope   = (const float*)d_in[9];
  const int*   qbo    = (const int*)d_in[10];
  float* out = (float*)d_out;
  const int n_q = in_sizes[0] / 256;
  const int nbo = in_sizes[10];

  char* p = (char*)d_ws;
  u16* krot = (u16*)p;                       p += (size_t)TOT_ROWS * 256 * 2;
  u16* vmap = (u16*)p;                       p += (size_t)TOT_ROWS * 256 * 2;
  float* qraw = (float*)p;                   p += (size_t)n_q * 256 * 4;
  u16* xbf = (u16*)p;                        p += (size_t)n_q * 256 * 2;
  u16* wtq = (u16*)p;                        p += 65536 * 2;
  u16* wtk = (u16*)p;                        p += 65536 * 2;
  u16* wtv = (u16*)p;                        p += 65536 * 2;
  u16* wto = (u16*)p;
  u16* ao = xbf;   // lifetimes disjoint

  hipLaunchKernelGGL(prep_kernel, dim3(128 + n_q / 4), dim3(256), 0, stream,
                     q_w, k_w, v_w, out_w, query, norm_w, norm_b,
                     wtq, wtk, wtv, wto, xbf);
  hipLaunchKernelGGL(kv_gemm, dim3(TOT_ROWS / 16), dim3(64), 0, stream,
                     fm, wtk, wtv, rope, krot, vmap);
  hipLaunchKernelGGL(gemm_xw, dim3(n_q / 16, 4), dim3(256), 0, stream,
                     xbf, wtq, (const float*)nullptr, qraw);
  hipLaunchKernelGGL(attn3, dim3(n_q), dim3(256), 0, stream,
                     qraw, qsp, rope, qbo, nbo, krot, vmap, ao);
  hipLaunchKernelGGL(gemm_xw, dim3(n_q / 16, 4), dim3(256), 0, stream,
                     ao, wto, query, out);
}

// Round 2
// 289.991 us; speedup vs baseline: 1.0053x; 1.0053x over previous
//
#include <hip/hip_runtime.h>
#include <hip/hip_bf16.h>

typedef unsigned short u16;
typedef short short8 __attribute__((ext_vector_type(8)));
typedef float f32x4 __attribute__((ext_vector_type(4)));

// EMBED=256, NH=8, HD=32, NPAIR=16, K_PER_Q=164; levels 128,64,32,16
// compact rows/batch = 16384+4096+1024+256 = 21760
#define ROWS_PER_BATCH 21760
#define TOT_ROWS 43520

__device__ __forceinline__ u16 f2bf(float f){
  unsigned u = __builtin_bit_cast(unsigned, f);
  u += 0x7FFFu + ((u >> 16) & 1u);
  return (u16)(u >> 16);
}
__device__ __forceinline__ float bf2f(u16 h){
  return __builtin_bit_cast(float, ((unsigned)h) << 16);
}
__device__ __forceinline__ float bflo(unsigned u){ return __builtin_bit_cast(float, u << 16); }
__device__ __forceinline__ float bfhi(unsigned u){ return __builtin_bit_cast(float, u & 0xFFFF0000u); }
__device__ __forceinline__ unsigned pk2bf(float a, float b){
  __hip_bfloat162 h = __float22bfloat162_rn(make_float2(a, b));
  union { __hip_bfloat162 h2; unsigned u; } cv; cv.h2 = h; return cv.u;
}

// ---------- prep: weight pack (blocks 0..127) + LayerNorm (blocks 128..) ----------
// packed[((cg*8 + kk)*64 + lane)*8 + j] = W[kk*32 + (lane>>4)*8 + j][cg*16 + (lane&15)]
__global__ __launch_bounds__(256) void prep_kernel(
    const float* __restrict__ qw, const float* __restrict__ kw,
    const float* __restrict__ vw, const float* __restrict__ ow,
    const float* __restrict__ q, const float* __restrict__ nw,
    const float* __restrict__ nb,
    u16* __restrict__ wtq, u16* __restrict__ wtk,
    u16* __restrict__ wtv, u16* __restrict__ wto, u16* __restrict__ x){
  const int bx = blockIdx.x;
  const int t = threadIdx.x;
  if (bx < 128){
    int e = bx * 256 + t;
    int which = e >> 13;
    int r = e & 8191;
    int cg = r >> 9;
    int kk = (r >> 6) & 7;
    int lane = r & 63;
    int quad = lane >> 4, mn = lane & 15;
    const float* s = which == 0 ? qw : which == 1 ? kw : which == 2 ? vw : ow;
    u16* d       = which == 0 ? wtq : which == 1 ? wtk : which == 2 ? wtv : wto;
    const float* base = s + (kk * 32 + quad * 8) * 256 + cg * 16 + mn;
    float e8[8];
    #pragma unroll
    for (int j = 0; j < 8; ++j) e8[j] = base[j * 256];
    uint4 o = { pk2bf(e8[0], e8[1]), pk2bf(e8[2], e8[3]),
                pk2bf(e8[4], e8[5]), pk2bf(e8[6], e8[7]) };
    *(uint4*)(d + (size_t)r * 8) = o;
  } else {
    const int row = (bx - 128) * 4 + (t >> 6);
    const int lane = t & 63;
    const float4 v = *(const float4*)(q + (size_t)row * 256 + lane * 4);
    float s1 = v.x + v.y + v.z + v.w;
    float s2 = v.x*v.x + v.y*v.y + v.z*v.z + v.w*v.w;
    #pragma unroll
    for (int o = 32; o > 0; o >>= 1){
      s1 += __shfl_xor(s1, o);
      s2 += __shfl_xor(s2, o);
    }
    float mu = s1 * (1.0f / 256.0f);
    float var = s2 * (1.0f / 256.0f) - mu * mu;
    float rs = rsqrtf(var + 1e-5f);
    const float4 wv = *(const float4*)(nw + lane * 4);
    const float4 bv = *(const float4*)(nb + lane * 4);
    float o0 = (v.x - mu) * rs * wv.x + bv.x;
    float o1 = (v.y - mu) * rs * wv.y + bv.y;
    float o2 = (v.z - mu) * rs * wv.z + bv.z;
    float o3 = (v.w - mu) * rs * wv.w + bv.w;
    uint2 pk = { pk2bf(o0, o1), pk2bf(o2, o3) };
    *(uint2*)(x + (size_t)row * 256 + lane * 4) = pk;
  }
}

// ---------- K+V map projection, fused K-RoPE. 1 wave/block, 32 ROWS, K AND V. ----------
// grid 1360 x 64 thr. Barrier-free. v2 changes vs 16-row version:
//  * 32 rows/block -> wtk+wtv L2 re-read halved (696 MB -> 348 MB total)
//  * B tiles streamed through a depth-8 rotating register queue (flattened
//    j = tl*8+kk loop, fully unrolled) -> ~8 KB per wave in flight, covers
//    L2 latency; with 1360 blocks all co-resident this is L2-BW-bound.
// FP accumulation order per output column is identical to the 16-row version.
__global__ __launch_bounds__(64, 2) void kv_gemm(const float* __restrict__ fm,
        const u16* __restrict__ wtkp, const u16* __restrict__ wtvp,
        const float* __restrict__ rope,
        u16* __restrict__ krot, u16* __restrict__ vmap){
  __shared__ float slab[32][66];
  __shared__ unsigned sh_cs[32][16];

  const int lane = threadIdx.x;
  const int row0 = blockIdx.x * 32;

  const int b = row0 / ROWS_PER_BATCH;
  const int rr = row0 - b * ROWS_PER_BATCH;
  int l, loff;
  if (rr < 16384)      { l = 0; loff = 0; }
  else if (rr < 20480) { l = 1; loff = 16384; }
  else if (rr < 21504) { l = 2; loff = 20480; }
  else                 { l = 3; loff = 21504; }
  const int logW = 7 - l;
  const int Wm1 = (128 >> l) - 1;
  const int cell0 = rr - loff;
  const float* fmbase = fm + (size_t)(b * 4 + l) * (128 * 128 * 256);

  const int mn = lane & 15;
  const int quad = lane >> 4;

  // A fragments straight from global (fp32 -> bf16 in regs); 2 row-groups
  short8 af[2][8];
  #pragma unroll
  for (int g = 0; g < 2; ++g){
    int cell = cell0 + g * 16 + mn;
    int y = cell >> logW, x = cell & Wm1;
    const float* arow = fmbase + (((y << 7) + x) << 8) + quad * 8;
    #pragma unroll
    for (int kk = 0; kk < 8; ++kk){
      float4 a0 = *(const float4*)(arow + kk * 32);
      float4 a1 = *(const float4*)(arow + kk * 32 + 4);
      union { short8 s; uint4 u; } cv;
      cv.u = (uint4){ pk2bf(a0.x, a0.y), pk2bf(a0.z, a0.w),
                      pk2bf(a1.x, a1.y), pk2bf(a1.z, a1.w) };
      af[g][kk] = cv.s;
    }
  }

  // cos/sin table: 32 rows x 16 pairs
  #pragma unroll
  for (int i = 0; i < 8; ++i){
    int id = i * 64 + lane;
    int lr = id >> 4, p = id & 15;
    int cell = cell0 + lr;
    int i0 = cell >> logW;
    int i1 = cell & Wm1;
    float fs = (float)(1 << l);
    float kx = ((float)i0 + 0.5f) * fs;
    float ky = ((float)i1 + 0.5f) * fs;
    float ang = kx * rope[p] + ky * rope[16 + p] + (float)l * rope[32 + p];
    sh_cs[lr][p] = pk2bf(__cosf(ang), __sinf(ang));
  }

  for (int m = 0; m < 2; ++m){
    const u16* wtp = m ? wtvp : wtkp;
    u16* outp = m ? vmap : krot;
    for (int cs2 = 0; cs2 < 4; ++cs2){
      // B tile stream for this 64-col group: 32 tiles (tl 0..3 x kk 0..7),
      // tile j at wb + j*512 u16.
      const u16* wb = wtp + (size_t)((cs2 * 32) * 64 + lane) * 8;
      short8 bq[8];
      #pragma unroll
      for (int j = 0; j < 8; ++j)
        bq[j] = *(const short8*)(wb + (size_t)j * 512);
      f32x4 acc0 = (f32x4){0.f, 0.f, 0.f, 0.f};
      f32x4 acc1 = (f32x4){0.f, 0.f, 0.f, 0.f};
      #pragma unroll
      for (int j = 0; j < 32; ++j){
        short8 bcur = bq[j & 7];
        if (j + 8 < 32)
          bq[j & 7] = *(const short8*)(wb + (size_t)(j + 8) * 512);
        const int kk = j & 7;
        acc0 = __builtin_amdgcn_mfma_f32_16x16x32_bf16(af[0][kk], bcur, acc0, 0, 0, 0);
        acc1 = __builtin_amdgcn_mfma_f32_16x16x32_bf16(af[1][kk], bcur, acc1, 0, 0, 0);
        if (kk == 7){
          const int tl = j >> 3;
          #pragma unroll
          for (int r = 0; r < 4; ++r){
            slab[quad * 4 + r][tl * 16 + mn]      = acc0[r];
            slab[16 + quad * 4 + r][tl * 16 + mn] = acc1[r];
          }
          acc0 = (f32x4){0.f, 0.f, 0.f, 0.f};
          acc1 = (f32x4){0.f, 0.f, 0.f, 0.f};
        }
      }
      // wave-local epilogue: slab transpose -> (RoPE) -> coalesced bf16 store
      #pragma unroll
      for (int i = 0; i < 16; ++i){
        int pi = i * 64 + lane;
        int row = pi >> 5;
        int pl = pi & 31;
        float2 kv2 = *(const float2*)&slab[row][pl * 2];
        unsigned o;
        if (m == 0){
          unsigned csn = sh_cs[row][pl & 15];
          float c = bflo(csn), s = bfhi(csn);
          o = pk2bf(kv2.x * c - kv2.y * s, kv2.x * s + kv2.y * c);
        } else {
          o = pk2bf(kv2.x, kv2.y);
        }
        *(unsigned*)(outp + (size_t)(row0 + row) * 256 + cs2 * 64 + pl * 2) = o;
      }
    }
  }
}

// ---------- barrier-free MFMA GEMM: out[M][256] = A(bf16) @ WT (+resid) ----------
__global__ __launch_bounds__(256) void gemm_xw(const u16* __restrict__ A,
        const u16* __restrict__ wt, const float* __restrict__ resid,
        float* __restrict__ out){
  const int t = threadIdx.x;
  const int row0 = blockIdx.x * 16;
  const int wv = t >> 6;
  const int lane = t & 63;
  const int mn = lane & 15;
  const int quad = lane >> 4;
  const int cg = blockIdx.y * 4 + wv;

  short8 af[8];
  {
    const u16* arow = A + (size_t)(row0 + mn) * 256 + quad * 8;
    #pragma unroll
    for (int kk = 0; kk < 8; ++kk)
      af[kk] = *(const short8*)(arow + kk * 32);
  }
  const u16* wb = wt + (size_t)((cg * 8) * 64 + lane) * 8;
  short8 bc = *(const short8*)wb;
  f32x4 acc = (f32x4){0.f, 0.f, 0.f, 0.f};
  #pragma unroll
  for (int kk = 0; kk < 8; ++kk){
    short8 bn;
    if (kk < 7) bn = *(const short8*)(wb + (size_t)(kk + 1) * 64 * 8);
    acc = __builtin_amdgcn_mfma_f32_16x16x32_bf16(af[kk], bc, acc, 0, 0, 0);
    bc = bn;
  }
  const int col = cg * 16 + mn;
  #pragma unroll
  for (int r = 0; r < 4; ++r){
    int row = row0 + quad * 4 + r;
    float val = acc[r];
    if (resid) val += resid[(size_t)row * 256 + col];
    out[(size_t)row * 256 + col] = val;
  }
}

// ---------- attention core: ONE WAVE PER QUERY, zero barriers ----------
// grid n_q/4 x 256 thr. All LDS is wave-private; intra-wave RAW ordered by lgkmcnt.
__global__ __launch_bounds__(256) void attn3(
    const float* __restrict__ qraw, const float* __restrict__ qsp,
    const float* __restrict__ rope, const int* __restrict__ qbo, int nbo,
    const u16* __restrict__ krot, const u16* __restrict__ vmap,
    u16* __restrict__ ao){
  __shared__ float sh_q[4][8][33];
  __shared__ float sh_lg[4][168][8];
  __shared__ int   sh_row[4][168];
  __shared__ float sh_inv[4][8];
  const int t = threadIdx.x;
  const int w = t >> 6;
  const int lane = t & 63;
  const int qi = blockIdx.x * 4 + w;

  int bidx = 0;
  for (int j = 1; j < nbo; ++j) if (qi >= qbo[j]) bidx = j;
  const float p0 = qsp[qi * 2 + 0];
  const float p1 = qsp[qi * 2 + 1];

  // q RoPE (1/sqrt(32) folded); 4 iters x 64 lanes cover 256 dims
  #pragma unroll
  for (int it = 0; it < 4; ++it){
    int d = it * 64 + lane;
    float qv = qraw[(size_t)qi * 256 + d];
    int p = (d & 31) >> 1;
    float ang = p0 * rope[p] + p1 * rope[16 + p];
    float c = __cosf(ang), s = __sinf(ang);
    float partner = __shfl_xor(qv, 1);
    float val = (d & 1) ? (partner * s + qv * c) : (qv * c - partner * s);
    sh_q[w][d >> 5][d & 31] = val * 0.17677669529663687f;
  }

  // key rows + validity
  #pragma unroll
  for (int it = 0; it < 3; ++it){
    int kk = it * 64 + lane;
    if (kk < 164){
      int l, dy, dx, loff;
      if (kk < 9)       { l = 0; int j = kk;      dy = j / 3 - 1; dx = j % 3 - 1; loff = 0; }
      else if (kk < 34) { l = 1; int j = kk - 9;  dy = j / 5 - 2; dx = j % 5 - 2; loff = 16384; }
      else if (kk < 83) { l = 2; int j = kk - 34; dy = j / 7 - 3; dx = j % 7 - 3; loff = 20480; }
      else              { l = 3; int j = kk - 83; dy = j / 9 - 4; dx = j % 9 - 4; loff = 21504; }
      float sc = 1.0f / (float)(1 << l);
      int i0 = (int)floorf(p0 * sc) + dy;
      int i1 = (int)floorf(p1 * sc) + dx;
      int W = 128 >> l;
      sh_row[w][kk] = (i0 < 0 || i0 >= W || i1 < 0 || i1 >= W)
                ? -1 : bidx * ROWS_PER_BATCH + loff + (i0 << (7 - l)) + i1;
    }
  }

  // logits: lane = (ksub, h); wave reads 8 contiguous 512B K rows per pass
  const int h = lane & 7;
  const int ksub = lane >> 3;
  float qreg[32];
  #pragma unroll
  for (int j = 0; j < 32; ++j) qreg[j] = sh_q[w][h][j];
  for (int pass = 0; pass < 21; ++pass){
    int kk = pass * 8 + ksub;
    if (kk < 164){
      int row = sh_row[w][kk];
      float lg = -1e9f;
      if (row >= 0){
        const uint4* kp = (const uint4*)(krot + (size_t)row * 256 + h * 32);
        uint4 A0 = kp[0], A1 = kp[1], A2 = kp[2], A3 = kp[3];
        unsigned uu[16];
        uu[0]=A0.x; uu[1]=A0.y; uu[2]=A0.z; uu[3]=A0.w;
        uu[4]=A1.x; uu[5]=A1.y; uu[6]=A1.z; uu[7]=A1.w;
        uu[8]=A2.x; uu[9]=A2.y; uu[10]=A2.z; uu[11]=A2.w;
        uu[12]=A3.x; uu[13]=A3.y; uu[14]=A3.z; uu[15]=A3.w;
        lg = 0.f;
        #pragma unroll
        for (int j = 0; j < 16; ++j)
          lg += qreg[2*j] * bflo(uu[j]) + qreg[2*j+1] * bfhi(uu[j]);
      }
      sh_lg[w][kk][h] = lg;
    }
  }

  // softmax: 8 lanes per head (xor 8/16/32 butterflies preserve h)
  float mx = -1e30f;
  for (int kk = ksub; kk < 164; kk += 8) mx = fmaxf(mx, sh_lg[w][kk][h]);
  #pragma unroll
  for (int o = 8; o < 64; o <<= 1) mx = fmaxf(mx, __shfl_xor(mx, o));
  float ssum = 0.f;
  for (int kk = ksub; kk < 164; kk += 8){
    float e = __expf(sh_lg[w][kk][h] - mx);    // invalid keys -> exactly 0
    sh_lg[w][kk][h] = e;
    ssum += e;
  }
  #pragma unroll
  for (int o = 8; o < 64; o <<= 1) ssum += __shfl_xor(ssum, o);
  if (ksub == 0) sh_inv[w][h] = 1.0f / ssum;

  // PV: lane owns 4 dims (8B coalesced V loads; 512B/wave per key)
  const int hh = lane >> 3;
  float a0 = 0.f, a1 = 0.f, a2 = 0.f, a3 = 0.f;
  #pragma unroll 4
  for (int kk = 0; kk < 164; ++kk){
    int row = sh_row[w][kk];
    int rc = row < 0 ? 0 : row;
    uint2 vv = *(const uint2*)(vmap + (size_t)rc * 256 + lane * 4);
    float e = sh_lg[w][kk][hh];
    a0 += e * bflo(vv.x);
    a1 += e * bfhi(vv.x);
    a2 += e * bflo(vv.y);
    a3 += e * bfhi(vv.y);
  }
  float inv = sh_inv[w][hh];
  uint2 o = { pk2bf(a0 * inv, a1 * inv), pk2bf(a2 * inv, a3 * inv) };
  *(uint2*)(ao + (size_t)qi * 256 + lane * 4) = o;
}

extern "C" void kernel_launch(void* const* d_in, const int* in_sizes, int n_in,
                              void* d_out, int out_size, void* d_ws, size_t ws_size,
                              hipStream_t stream) {
  (void)n_in; (void)out_size; (void)ws_size;
  const float* query  = (const float*)d_in[0];
  const float* qsp    = (const float*)d_in[1];
  const float* fm     = (const float*)d_in[2];
  const float* norm_w = (const float*)d_in[3];
  const float* norm_b = (const float*)d_in[4];
  const float* q_w    = (const float*)d_in[5];
  const float* k_w    = (const float*)d_in[6];
  const float* v_w    = (const float*)d_in[7];
  const float* out_w  = (const float*)d_in[8];
  const float* rope   = (const float*)d_in[9];
  const int*   qbo    = (const int*)d_in[10];
  float* out = (float*)d_out;
  const int n_q = in_sizes[0] / 256;
  const int nbo = in_sizes[10];

  char* p = (char*)d_ws;
  u16* krot = (u16*)p;                       p += (size_t)TOT_ROWS * 256 * 2;
  u16* vmap = (u16*)p;                       p += (size_t)TOT_ROWS * 256 * 2;
  float* qraw = (float*)p;                   p += (size_t)n_q * 256 * 4;
  u16* xbf = (u16*)p;                        p += (size_t)n_q * 256 * 2;
  u16* wtq = (u16*)p;                        p += 65536 * 2;
  u16* wtk = (u16*)p;                        p += 65536 * 2;
  u16* wtv = (u16*)p;                        p += 65536 * 2;
  u16* wto = (u16*)p;
  u16* ao = xbf;   // lifetimes disjoint

  hipLaunchKernelGGL(prep_kernel, dim3(128 + n_q / 4), dim3(256), 0, stream,
                     q_w, k_w, v_w, out_w, query, norm_w, norm_b,
                     wtq, wtk, wtv, wto, xbf);
  hipLaunchKernelGGL(kv_gemm, dim3(TOT_ROWS / 32), dim3(64), 0, stream,
                     fm, wtk, wtv, rope, krot, vmap);
  hipLaunchKernelGGL(gemm_xw, dim3(n_q / 16, 4), dim3(256), 0, stream,
                     xbf, wtq, (const float*)nullptr, qraw);
  hipLaunchKernelGGL(attn3, dim3(n_q / 4), dim3(256), 0, stream,
                     qraw, qsp, rope, qbo, nbo, krot, vmap, ao);
  hipLaunchKernelGGL(gemm_xw, dim3(n_q / 16, 4), dim3(256), 0, stream,
                     ao, wto, query, out);
}

// Round 3
// 270.764 us; speedup vs baseline: 1.0766x; 1.0710x over previous
//
#include <hip/hip_runtime.h>
#include <hip/hip_bf16.h>

typedef unsigned short u16;
typedef short short8 __attribute__((ext_vector_type(8)));
typedef float f32x4 __attribute__((ext_vector_type(4)));

// EMBED=256, NH=8, HD=32, NPAIR=16, K_PER_Q=164; levels 128,64,32,16
// compact rows/batch = 16384+4096+1024+256 = 21760
#define ROWS_PER_BATCH 21760
#define TOT_ROWS 43520

__device__ __forceinline__ u16 f2bf(float f){
  unsigned u = __builtin_bit_cast(unsigned, f);
  u += 0x7FFFu + ((u >> 16) & 1u);
  return (u16)(u >> 16);
}
__device__ __forceinline__ float bf2f(u16 h){
  return __builtin_bit_cast(float, ((unsigned)h) << 16);
}
__device__ __forceinline__ float bflo(unsigned u){ return __builtin_bit_cast(float, u << 16); }
__device__ __forceinline__ float bfhi(unsigned u){ return __builtin_bit_cast(float, u & 0xFFFF0000u); }
__device__ __forceinline__ unsigned pk2bf(float a, float b){
  __hip_bfloat162 h = __float22bfloat162_rn(make_float2(a, b));
  union { __hip_bfloat162 h2; unsigned u; } cv; cv.h2 = h; return cv.u;
}

// ---------- prep: weight pack (blocks 0..127) + LayerNorm (blocks 128..) ----------
// packed[((cg*8 + kk)*64 + lane)*8 + j] = W[kk*32 + (lane>>4)*8 + j][cg*16 + (lane&15)]
__global__ __launch_bounds__(256) void prep_kernel(
    const float* __restrict__ qw, const float* __restrict__ kw,
    const float* __restrict__ vw, const float* __restrict__ ow,
    const float* __restrict__ q, const float* __restrict__ nw,
    const float* __restrict__ nb,
    u16* __restrict__ wtq, u16* __restrict__ wtk,
    u16* __restrict__ wtv, u16* __restrict__ wto, u16* __restrict__ x){
  const int bx = blockIdx.x;
  const int t = threadIdx.x;
  if (bx < 128){
    int e = bx * 256 + t;
    int which = e >> 13;
    int r = e & 8191;
    int cg = r >> 9;
    int kk = (r >> 6) & 7;
    int lane = r & 63;
    int quad = lane >> 4, mn = lane & 15;
    const float* s = which == 0 ? qw : which == 1 ? kw : which == 2 ? vw : ow;
    u16* d       = which == 0 ? wtq : which == 1 ? wtk : which == 2 ? wtv : wto;
    const float* base = s + (kk * 32 + quad * 8) * 256 + cg * 16 + mn;
    float e8[8];
    #pragma unroll
    for (int j = 0; j < 8; ++j) e8[j] = base[j * 256];
    uint4 o = { pk2bf(e8[0], e8[1]), pk2bf(e8[2], e8[3]),
                pk2bf(e8[4], e8[5]), pk2bf(e8[6], e8[7]) };
    *(uint4*)(d + (size_t)r * 8) = o;
  } else {
    const int row = (bx - 128) * 4 + (t >> 6);
    const int lane = t & 63;
    const float4 v = *(const float4*)(q + (size_t)row * 256 + lane * 4);
    float s1 = v.x + v.y + v.z + v.w;
    float s2 = v.x*v.x + v.y*v.y + v.z*v.z + v.w*v.w;
    #pragma unroll
    for (int o = 32; o > 0; o >>= 1){
      s1 += __shfl_xor(s1, o);
      s2 += __shfl_xor(s2, o);
    }
    float mu = s1 * (1.0f / 256.0f);
    float var = s2 * (1.0f / 256.0f) - mu * mu;
    float rs = rsqrtf(var + 1e-5f);
    const float4 wv = *(const float4*)(nw + lane * 4);
    const float4 bv = *(const float4*)(nb + lane * 4);
    float o0 = (v.x - mu) * rs * wv.x + bv.x;
    float o1 = (v.y - mu) * rs * wv.y + bv.y;
    float o2 = (v.z - mu) * rs * wv.z + bv.z;
    float o3 = (v.w - mu) * rs * wv.w + bv.w;
    uint2 pk = { pk2bf(o0, o1), pk2bf(o2, o3) };
    *(uint2*)(x + (size_t)row * 256 + lane * 4) = pk;
  }
}

// ---------- K+V map projection, fused K-RoPE. 1 wave/block, 16 rows, K AND V. ----------
// grid 2720 x 64 thr. Barrier-free; A fragments loaded once, reused for K and V.
// NOTE: 32-row variant (half the blocks) measured +17 us — occupancy-bound, keep 16.
__global__ __launch_bounds__(64, 4) void kv_gemm(const float* __restrict__ fm,
        const u16* __restrict__ wtkp, const u16* __restrict__ wtvp,
        const float* __restrict__ rope,
        u16* __restrict__ krot, u16* __restrict__ vmap){
  __shared__ float slab[16][66];
  __shared__ unsigned sh_cs[16][16];

  const int lane = threadIdx.x;
  const int row0 = blockIdx.x * 16;

  const int b = row0 / ROWS_PER_BATCH;
  const int rr = row0 - b * ROWS_PER_BATCH;
  int l, loff;
  if (rr < 16384)      { l = 0; loff = 0; }
  else if (rr < 20480) { l = 1; loff = 16384; }
  else if (rr < 21504) { l = 2; loff = 20480; }
  else                 { l = 3; loff = 21504; }
  const int logW = 7 - l;
  const int Wm1 = (128 >> l) - 1;
  const int cell0 = rr - loff;
  const float* fmbase = fm + (size_t)(b * 4 + l) * (128 * 128 * 256);

  const int mn = lane & 15;
  const int quad = lane >> 4;

  // A fragments straight from global (fp32 -> bf16 in regs)
  short8 af[8];
  {
    int cell = cell0 + mn;
    int y = cell >> logW, x = cell & Wm1;
    const float* arow = fmbase + (((y << 7) + x) << 8) + quad * 8;
    #pragma unroll
    for (int kk = 0; kk < 8; ++kk){
      float4 a0 = *(const float4*)(arow + kk * 32);
      float4 a1 = *(const float4*)(arow + kk * 32 + 4);
      union { short8 s; uint4 u; } cv;
      cv.u = (uint4){ pk2bf(a0.x, a0.y), pk2bf(a0.z, a0.w),
                      pk2bf(a1.x, a1.y), pk2bf(a1.z, a1.w) };
      af[kk] = cv.s;
    }
  }

  // cos/sin table: 16 rows x 16 pairs
  #pragma unroll
  for (int i = 0; i < 4; ++i){
    int id = i * 64 + lane;
    int lr = id >> 4, p = id & 15;
    int cell = cell0 + lr;
    int i0 = cell >> logW;
    int i1 = cell & Wm1;
    float fs = (float)(1 << l);
    float kx = ((float)i0 + 0.5f) * fs;
    float ky = ((float)i1 + 0.5f) * fs;
    float ang = kx * rope[p] + ky * rope[16 + p] + (float)l * rope[32 + p];
    sh_cs[lr][p] = pk2bf(__cosf(ang), __sinf(ang));
  }

  for (int m = 0; m < 2; ++m){
    const u16* wtp = m ? wtvp : wtkp;
    u16* outp = m ? vmap : krot;
    for (int cs2 = 0; cs2 < 4; ++cs2){
      const u16* wb = wtp + (size_t)((cs2 * 4 * 8) * 64 + lane) * 8;
      short8 bc[4], bn[4];
      #pragma unroll
      for (int tl = 0; tl < 4; ++tl)
        bc[tl] = *(const short8*)(wb + (size_t)(tl * 8) * 64 * 8);
      f32x4 acc[4];
      #pragma unroll
      for (int i = 0; i < 4; ++i) acc[i] = (f32x4){0.f, 0.f, 0.f, 0.f};
      #pragma unroll
      for (int kk = 0; kk < 8; ++kk){
        if (kk < 7){
          #pragma unroll
          for (int tl = 0; tl < 4; ++tl)
            bn[tl] = *(const short8*)(wb + (size_t)(tl * 8 + kk + 1) * 64 * 8);
        }
        #pragma unroll
        for (int tl = 0; tl < 4; ++tl)
          acc[tl] = __builtin_amdgcn_mfma_f32_16x16x32_bf16(af[kk], bc[tl], acc[tl], 0, 0, 0);
        #pragma unroll
        for (int tl = 0; tl < 4; ++tl) bc[tl] = bn[tl];
      }
      // wave-local epilogue: slab transpose -> (RoPE) -> coalesced bf16 store
      #pragma unroll
      for (int tl = 0; tl < 4; ++tl)
        #pragma unroll
        for (int r = 0; r < 4; ++r)
          slab[quad * 4 + r][tl * 16 + mn] = acc[tl][r];
      #pragma unroll
      for (int i = 0; i < 8; ++i){
        int pi = i * 64 + lane;
        int row = pi >> 5;
        int pl = pi & 31;
        float2 kv2 = *(const float2*)&slab[row][pl * 2];
        unsigned o;
        if (m == 0){
          unsigned csn = sh_cs[row][pl & 15];
          float c = bflo(csn), s = bfhi(csn);
          o = pk2bf(kv2.x * c - kv2.y * s, kv2.x * s + kv2.y * c);
        } else {
          o = pk2bf(kv2.x, kv2.y);
        }
        *(unsigned*)(outp + (size_t)(row0 + row) * 256 + cs2 * 64 + pl * 2) = o;
      }
    }
  }
}

// ---------- barrier-free MFMA GEMM: out[M][256] = A(bf16) @ WT (+resid) ----------
__global__ __launch_bounds__(256) void gemm_xw(const u16* __restrict__ A,
        const u16* __restrict__ wt, const float* __restrict__ resid,
        float* __restrict__ out){
  const int t = threadIdx.x;
  const int row0 = blockIdx.x * 16;
  const int wv = t >> 6;
  const int lane = t & 63;
  const int mn = lane & 15;
  const int quad = lane >> 4;
  const int cg = blockIdx.y * 4 + wv;

  short8 af[8];
  {
    const u16* arow = A + (size_t)(row0 + mn) * 256 + quad * 8;
    #pragma unroll
    for (int kk = 0; kk < 8; ++kk)
      af[kk] = *(const short8*)(arow + kk * 32);
  }
  const u16* wb = wt + (size_t)((cg * 8) * 64 + lane) * 8;
  short8 bc = *(const short8*)wb;
  f32x4 acc = (f32x4){0.f, 0.f, 0.f, 0.f};
  #pragma unroll
  for (int kk = 0; kk < 8; ++kk){
    short8 bn;
    if (kk < 7) bn = *(const short8*)(wb + (size_t)(kk + 1) * 64 * 8);
    acc = __builtin_amdgcn_mfma_f32_16x16x32_bf16(af[kk], bc, acc, 0, 0, 0);
    bc = bn;
  }
  const int col = cg * 16 + mn;
  #pragma unroll
  for (int r = 0; r < 4; ++r){
    int row = row0 + quad * 4 + r;
    float val = acc[r];
    if (resid) val += resid[(size_t)row * 256 + col];
    out[(size_t)row * 256 + col] = val;
  }
}

// ---------- attention core: ONE WAVE PER QUERY, zero barriers ----------
// grid n_q/4 x 256 thr. All LDS is wave-private; intra-wave RAW ordered by lgkmcnt.
// v3 (surgical, structure identical to the 272us v1):
//  * logit dot product split into 4 independent partial sums (dependent-FMA
//    chain 32 -> 8 per pass; no fast-math so compiler can't reassociate)
//  * PV processes 2 keys/iter with 16B V loads (82 iters instead of 164;
//    lane = key-parity x 8-dim group; one shfl_xor(32) merge at the end)
__global__ __launch_bounds__(256) void attn3(
    const float* __restrict__ qraw, const float* __restrict__ qsp,
    const float* __restrict__ rope, const int* __restrict__ qbo, int nbo,
    const u16* __restrict__ krot, const u16* __restrict__ vmap,
    u16* __restrict__ ao){
  __shared__ float sh_q[4][8][33];
  __shared__ float sh_lg[4][168][8];
  __shared__ int   sh_row[4][168];
  __shared__ float sh_inv[4][8];
  const int t = threadIdx.x;
  const int w = t >> 6;
  const int lane = t & 63;
  const int qi = blockIdx.x * 4 + w;

  int bidx = 0;
  for (int j = 1; j < nbo; ++j) if (qi >= qbo[j]) bidx = j;
  const float p0 = qsp[qi * 2 + 0];
  const float p1 = qsp[qi * 2 + 1];

  // q RoPE (1/sqrt(32) folded); 4 iters x 64 lanes cover 256 dims
  #pragma unroll
  for (int it = 0; it < 4; ++it){
    int d = it * 64 + lane;
    float qv = qraw[(size_t)qi * 256 + d];
    int p = (d & 31) >> 1;
    float ang = p0 * rope[p] + p1 * rope[16 + p];
    float c = __cosf(ang), s = __sinf(ang);
    float partner = __shfl_xor(qv, 1);
    float val = (d & 1) ? (partner * s + qv * c) : (qv * c - partner * s);
    sh_q[w][d >> 5][d & 31] = val * 0.17677669529663687f;
  }

  // key rows + validity
  #pragma unroll
  for (int it = 0; it < 3; ++it){
    int kk = it * 64 + lane;
    if (kk < 164){
      int l, dy, dx, loff;
      if (kk < 9)       { l = 0; int j = kk;      dy = j / 3 - 1; dx = j % 3 - 1; loff = 0; }
      else if (kk < 34) { l = 1; int j = kk - 9;  dy = j / 5 - 2; dx = j % 5 - 2; loff = 16384; }
      else if (kk < 83) { l = 2; int j = kk - 34; dy = j / 7 - 3; dx = j % 7 - 3; loff = 20480; }
      else              { l = 3; int j = kk - 83; dy = j / 9 - 4; dx = j % 9 - 4; loff = 21504; }
      float sc = 1.0f / (float)(1 << l);
      int i0 = (int)floorf(p0 * sc) + dy;
      int i1 = (int)floorf(p1 * sc) + dx;
      int W = 128 >> l;
      sh_row[w][kk] = (i0 < 0 || i0 >= W || i1 < 0 || i1 >= W)
                ? -1 : bidx * ROWS_PER_BATCH + loff + (i0 << (7 - l)) + i1;
    }
  }

  // logits: lane = (ksub, h); wave reads 8 contiguous 512B K rows per pass
  const int h = lane & 7;
  const int ksub = lane >> 3;
  float qreg[32];
  #pragma unroll
  for (int j = 0; j < 32; ++j) qreg[j] = sh_q[w][h][j];
  for (int pass = 0; pass < 21; ++pass){
    int kk = pass * 8 + ksub;
    if (kk < 164){
      int row = sh_row[w][kk];
      float lg = -1e9f;
      if (row >= 0){
        const uint4* kp = (const uint4*)(krot + (size_t)row * 256 + h * 32);
        uint4 A0 = kp[0], A1 = kp[1], A2 = kp[2], A3 = kp[3];
        unsigned uu[16];
        uu[0]=A0.x; uu[1]=A0.y; uu[2]=A0.z; uu[3]=A0.w;
        uu[4]=A1.x; uu[5]=A1.y; uu[6]=A1.z; uu[7]=A1.w;
        uu[8]=A2.x; uu[9]=A2.y; uu[10]=A2.z; uu[11]=A2.w;
        uu[12]=A3.x; uu[13]=A3.y; uu[14]=A3.z; uu[15]=A3.w;
        // 4 independent partial sums -> dependent-FMA chain 8 deep, not 32
        float s0 = 0.f, s1 = 0.f, s2 = 0.f, s3 = 0.f;
        #pragma unroll
        for (int j = 0; j < 4; ++j){
          s0 += qreg[2*j]      * bflo(uu[j])      + qreg[2*j+1]  * bfhi(uu[j]);
          s1 += qreg[2*j+8]    * bflo(uu[j+4])    + qreg[2*j+9]  * bfhi(uu[j+4]);
          s2 += qreg[2*j+16]   * bflo(uu[j+8])    + qreg[2*j+17] * bfhi(uu[j+8]);
          s3 += qreg[2*j+24]   * bflo(uu[j+12])   + qreg[2*j+25] * bfhi(uu[j+12]);
        }
        lg = (s0 + s1) + (s2 + s3);
      }
      sh_lg[w][kk][h] = lg;
    }
  }

  // softmax: 8 lanes per head (xor 8/16/32 butterflies preserve h)
  float mx = -1e30f;
  for (int kk = ksub; kk < 164; kk += 8) mx = fmaxf(mx, sh_lg[w][kk][h]);
  #pragma unroll
  for (int o = 8; o < 64; o <<= 1) mx = fmaxf(mx, __shfl_xor(mx, o));
  float ssum = 0.f;
  for (int kk = ksub; kk < 164; kk += 8){
    float e = __expf(sh_lg[w][kk][h] - mx);    // invalid keys -> exactly 0
    sh_lg[w][kk][h] = e;
    ssum += e;
  }
  #pragma unroll
  for (int o = 8; o < 64; o <<= 1) ssum += __shfl_xor(ssum, o);
  if (ksub == 0) sh_inv[w][h] = 1.0f / ssum;

  // PV: 2 keys/iter; lane = (parity, 8-dim group); 16B coalesced V loads
  const int c = lane & 31;        // dims c*8 .. c*8+7
  const int p2 = lane >> 5;       // key parity
  const int hh = c >> 2;          // head of this dim group
  float a[8] = {0.f,0.f,0.f,0.f,0.f,0.f,0.f,0.f};
  #pragma unroll 4
  for (int ii = 0; ii < 82; ++ii){
    int kk = ii * 2 + p2;
    int row = sh_row[w][kk];
    int rc = row < 0 ? 0 : row;
    uint4 vv = *(const uint4*)(vmap + (size_t)rc * 256 + c * 8);
    float e = sh_lg[w][kk][hh];   // invalid -> 0
    a[0] += e * bflo(vv.x); a[1] += e * bfhi(vv.x);
    a[2] += e * bflo(vv.y); a[3] += e * bfhi(vv.y);
    a[4] += e * bflo(vv.z); a[5] += e * bfhi(vv.z);
    a[6] += e * bflo(vv.w); a[7] += e * bfhi(vv.w);
  }
  #pragma unroll
  for (int j = 0; j < 8; ++j) a[j] += __shfl_xor(a[j], 32);
  if (p2 == 0){
    float inv = sh_inv[w][hh];
    uint4 o = { pk2bf(a[0]*inv, a[1]*inv), pk2bf(a[2]*inv, a[3]*inv),
                pk2bf(a[4]*inv, a[5]*inv), pk2bf(a[6]*inv, a[7]*inv) };
    *(uint4*)(ao + (size_t)qi * 256 + c * 8) = o;
  }
}

extern "C" void kernel_launch(void* const* d_in, const int* in_sizes, int n_in,
                              void* d_out, int out_size, void* d_ws, size_t ws_size,
                              hipStream_t stream) {
  (void)n_in; (void)out_size; (void)ws_size;
  const float* query  = (const float*)d_in[0];
  const float* qsp    = (const float*)d_in[1];
  const float* fm     = (const float*)d_in[2];
  const float* norm_w = (const float*)d_in[3];
  const float* norm_b = (const float*)d_in[4];
  const float* q_w    = (const float*)d_in[5];
  const float* k_w    = (const float*)d_in[6];
  const float* v_w    = (const float*)d_in[7];
  const float* out_w  = (const float*)d_in[8];
  const float* rope   = (const float*)d_in[9];
  const int*   qbo    = (const int*)d_in[10];
  float* out = (float*)d_out;
  const int n_q = in_sizes[0] / 256;
  const int nbo = in_sizes[10];

  char* p = (char*)d_ws;
  u16* krot = (u16*)p;                       p += (size_t)TOT_ROWS * 256 * 2;
  u16* vmap = (u16*)p;                       p += (size_t)TOT_ROWS * 256 * 2;
  float* qraw = (float*)p;                   p += (size_t)n_q * 256 * 4;
  u16* xbf = (u16*)p;                        p += (size_t)n_q * 256 * 2;
  u16* wtq = (u16*)p;                        p += 65536 * 2;
  u16* wtk = (u16*)p;                        p += 65536 * 2;
  u16* wtv = (u16*)p;                        p += 65536 * 2;
  u16* wto = (u16*)p;
  u16* ao = xbf;   // lifetimes disjoint

  hipLaunchKernelGGL(prep_kernel, dim3(128 + n_q / 4), dim3(256), 0, stream,
                     q_w, k_w, v_w, out_w, query, norm_w, norm_b,
                     wtq, wtk, wtv, wto, xbf);
  hipLaunchKernelGGL(kv_gemm, dim3(TOT_ROWS / 16), dim3(64), 0, stream,
                     fm, wtk, wtv, rope, krot, vmap);
  hipLaunchKernelGGL(gemm_xw, dim3(n_q / 16, 4), dim3(256), 0, stream,
                     xbf, wtq, (const float*)nullptr, qraw);
  hipLaunchKernelGGL(attn3, dim3(n_q / 4), dim3(256), 0, stream,
                     qraw, qsp, rope, qbo, nbo, krot, vmap, ao);
  hipLaunchKernelGGL(gemm_xw, dim3(n_q / 16, 4), dim3(256), 0, stream,
                     ao, wto, query, out);
}